// Round 6
// baseline (19.819 us; speedup 1.0000x reference)
//
#include <hip/hip_runtime.h>

#define K        256
#define NEDGE    257
#define NPTS     76800            // 240*320
#define THREADS  256
#define R1B      256              // role-1 blocks: 128 per batch, 2 centers each
#define R2CH     300              // role-2 chunks per batch (256 pts each)
#define R2B      (2 * R2CH)       // 600
#define NBLOCKS  (R1B + R2B)      // 856

// ws layout (all cross-block data written via agent-scope (sc1) stores every call):
//   uint  ticket           @ byte 0     (monotonic across calls; checked mod NBLOCKS)
//   float centerMin[2*K]   @ byte 64
//   float partials[R2B]    @ byte 2176

__global__ __launch_bounds__(THREADS)
void chamfer_one(const float* __restrict__ target,
                 const float* __restrict__ edges,
                 unsigned int* __restrict__ ticket,
                 float* __restrict__ centerMin,
                 float* __restrict__ partials,
                 float* __restrict__ out) {
    const int t = threadIdx.x;
    __shared__ float sRedA[THREADS];
    __shared__ float sRedB[THREADS];
    __shared__ int   sIsLast;

    if (blockIdx.x < R1B) {
        // ---- role 1: one block owns 2 centers, scans ALL points of its batch ----
        const int b  = blockIdx.x >> 7;
        const int c0 = 2 * (blockIdx.x & 127);
        const float* e = edges + b * NEDGE;
        const float cA = 0.5f * (e[c0]     + e[c0 + 1]);
        const float cB = 0.5f * (e[c0 + 1] + e[c0 + 2]);

        const float4* p4 = (const float4*)(target + (size_t)b * NPTS);
        float a0 = 1e30f, a1 = 1e30f, b0 = 1e30f, b1 = 1e30f;
        #pragma unroll 5
        for (int i = 0; i < NPTS / 4 / THREADS; ++i) {
            const float4 p = p4[(size_t)i * THREADS + t];
            float x;
            x = p.x - cA; a0 = fminf(a0, x * x);
            x = p.y - cA; a1 = fminf(a1, x * x);
            x = p.z - cA; a0 = fminf(a0, x * x);
            x = p.w - cA; a1 = fminf(a1, x * x);
            x = p.x - cB; b0 = fminf(b0, x * x);
            x = p.y - cB; b1 = fminf(b1, x * x);
            x = p.z - cB; b0 = fminf(b0, x * x);
            x = p.w - cB; b1 = fminf(b1, x * x);
        }
        sRedA[t] = fminf(a0, a1);
        sRedB[t] = fminf(b0, b1);
        __syncthreads();
        for (int s = THREADS / 2; s > 0; s >>= 1) {
            if (t < s) {
                sRedA[t] = fminf(sRedA[t], sRedA[t + s]);
                sRedB[t] = fminf(sRedB[t], sRedB[t + s]);
            }
            __syncthreads();
        }
        if (t == 0) {
            __hip_atomic_store(&centerMin[b * K + c0],     sRedA[0],
                               __ATOMIC_RELAXED, __HIP_MEMORY_SCOPE_AGENT);
            __hip_atomic_store(&centerMin[b * K + c0 + 1], sRedB[0],
                               __ATOMIC_RELAXED, __HIP_MEMORY_SCOPE_AGENT);
        }
    } else {
        // ---- role 2: each thread's point vs all 256 centers ----
        const int blk2  = blockIdx.x - R1B;
        const int b     = blk2 / R2CH;
        const int chunk = blk2 % R2CH;
        __shared__ float sC[K];
        const float* e = edges + b * NEDGE;
        sC[t] = 0.5f * (e[t] + e[t + 1]);
        const float d = target[(size_t)b * NPTS + (size_t)chunk * THREADS + t];
        __syncthreads();

        float m0 = 1e30f, m1 = 1e30f, m2 = 1e30f, m3 = 1e30f;
        const float4* c4 = (const float4*)sC;    // uniform addr -> LDS broadcast
        #pragma unroll 16
        for (int i = 0; i < K / 4; ++i) {
            const float4 c = c4[i];
            float x;
            x = d - c.x; m0 = fminf(m0, x * x);
            x = d - c.y; m1 = fminf(m1, x * x);
            x = d - c.z; m2 = fminf(m2, x * x);
            x = d - c.w; m3 = fminf(m3, x * x);
        }
        sRedA[t] = fminf(fminf(m0, m1), fminf(m2, m3));
        __syncthreads();
        for (int s = THREADS / 2; s > 0; s >>= 1) {
            if (t < s) sRedA[t] += sRedA[t + s];
            __syncthreads();
        }
        if (t == 0)
            __hip_atomic_store(&partials[blk2], sRedA[0],
                               __ATOMIC_RELAXED, __HIP_MEMORY_SCOPE_AGENT);
    }

    // ---- ticket: relaxed agent add; 856th ticket of this call's window finishes ----
    if (t == 0) {
        asm volatile("s_waitcnt vmcnt(0)" ::: "memory");  // sc1 stores are at LLC
        unsigned int old = __hip_atomic_fetch_add(ticket, 1u, __ATOMIC_RELAXED,
                                                  __HIP_MEMORY_SCOPE_AGENT);
        sIsLast = ((old % NBLOCKS) == (NBLOCKS - 1));
    }
    __syncthreads();
    if (!sIsLast) return;

    // ---- last block: final reduction, fixed order -> deterministic ----
    float s = __hip_atomic_load(&centerMin[t],           __ATOMIC_RELAXED,
                                __HIP_MEMORY_SCOPE_AGENT)
            + __hip_atomic_load(&centerMin[t + THREADS], __ATOMIC_RELAXED,
                                __HIP_MEMORY_SCOPE_AGENT);
    for (int i = t; i < R2B; i += THREADS)
        s += __hip_atomic_load(&partials[i], __ATOMIC_RELAXED,
                               __HIP_MEMORY_SCOPE_AGENT);
    sRedA[t] = s;
    __syncthreads();
    for (int st = THREADS / 2; st > 0; st >>= 1) {
        if (t < st) sRedA[t] += sRedA[t + st];
        __syncthreads();
    }
    if (t == 0) out[0] = 0.5f * sRedA[0];   // mean over B=2
}

extern "C" void kernel_launch(void* const* d_in, const int* in_sizes, int n_in,
                              void* d_out, int out_size, void* d_ws, size_t ws_size,
                              hipStream_t stream) {
    const float* target = (const float*)d_in[0];   // [2,1,240,320] fp32
    const float* edges  = (const float*)d_in[1];   // [2,257] fp32
    float* out = (float*)d_out;

    unsigned int* ticket    = (unsigned int*)d_ws;
    float*        centerMin = (float*)((char*)d_ws + 64);     // 512 floats
    float*        partials  = (float*)((char*)d_ws + 2176);   // 600 floats

    chamfer_one<<<NBLOCKS, THREADS, 0, stream>>>(target, edges, ticket,
                                                 centerMin, partials, out);
}

// Round 7
// 14.456 us; speedup vs baseline: 1.3710x; 1.3710x over previous
//
#include <hip/hip_runtime.h>

#define K        256
#define NEDGE    257
#define NPTS     76800            // 240*320
#define THREADS  256
#define R1B      512              // role-1: 256 blocks per batch, 1 center each
#define R2CH     300              // role-2 chunks per batch (256 pts each)
#define R2B      (2 * R2CH)       // 600
#define NBLOCKS  (R1B + R2B)      // 1112

// ws layout (no init needed — all written before read, every call):
//   float centerMin[2*K]   @ byte 0     (role-1 output)
//   float partials[R2B]    @ byte 2048  (role-2 output)

__global__ __launch_bounds__(THREADS)
void chamfer_a(const float* __restrict__ target,
               const float* __restrict__ edges,
               float* __restrict__ centerMin,
               float* __restrict__ partials) {
    const int t = threadIdx.x;

    if (blockIdx.x < R1B) {
        // ---- role 1: one block owns ONE center, scans all points of its batch ----
        const int b = blockIdx.x >> 8;           // 256 blocks per batch
        const int c0 = blockIdx.x & 255;
        const float* e = edges + b * NEDGE;
        const float c = 0.5f * (e[c0] + e[c0 + 1]);

        const float4* p4 = (const float4*)(target + (size_t)b * NPTS);
        float m0 = 1e30f, m1 = 1e30f, m2 = 1e30f, m3 = 1e30f;
        #pragma unroll 5
        for (int i = 0; i < NPTS / 4 / THREADS; ++i) {   // 75 coalesced float4 iters
            const float4 p = p4[(size_t)i * THREADS + t];
            float x;
            x = p.x - c; m0 = fminf(m0, x * x);
            x = p.y - c; m1 = fminf(m1, x * x);
            x = p.z - c; m2 = fminf(m2, x * x);
            x = p.w - c; m3 = fminf(m3, x * x);
        }
        __shared__ float sRed[THREADS];
        sRed[t] = fminf(fminf(m0, m1), fminf(m2, m3));
        __syncthreads();
        for (int s = THREADS / 2; s > 0; s >>= 1) {
            if (t < s) sRed[t] = fminf(sRed[t], sRed[t + s]);
            __syncthreads();
        }
        if (t == 0) centerMin[b * K + c0] = sRed[0];
    } else {
        // ---- role 2: each thread's point vs 256 centers, fma form ----
        // min_c (d-c)^2 = d^2 + min_c (c^2 - 2dc)
        const int blk2  = blockIdx.x - R1B;
        const int b     = blk2 / R2CH;
        const int chunk = blk2 % R2CH;
        __shared__ float sC2[K];    // c^2
        __shared__ float sM2C[K];   // -2c
        __shared__ float sRed[THREADS];
        const float* e = edges + b * NEDGE;
        {
            const float c = 0.5f * (e[t] + e[t + 1]);
            sC2[t]  = c * c;
            sM2C[t] = -2.0f * c;
        }
        const float d = target[(size_t)b * NPTS + (size_t)chunk * THREADS + t];
        __syncthreads();

        float m0 = 1e30f, m1 = 1e30f, m2 = 1e30f, m3 = 1e30f;
        const float4* c2v  = (const float4*)sC2;    // uniform addr -> LDS broadcast
        const float4* m2cv = (const float4*)sM2C;
        #pragma unroll 16
        for (int i = 0; i < K / 4; ++i) {
            const float4 c2 = c2v[i];
            const float4 mc = m2cv[i];
            m0 = fminf(m0, fmaf(mc.x, d, c2.x));
            m1 = fminf(m1, fmaf(mc.y, d, c2.y));
            m2 = fminf(m2, fmaf(mc.z, d, c2.z));
            m3 = fminf(m3, fmaf(mc.w, d, c2.w));
        }
        // this point's min distance^2 = d^2 + min(...)  (>= 0 mathematically)
        sRed[t] = fmaf(d, d, fminf(fminf(m0, m1), fminf(m2, m3)));
        __syncthreads();
        for (int s = THREADS / 2; s > 0; s >>= 1) {      // fixed-tree SUM
            if (t < s) sRed[t] += sRed[t + s];
            __syncthreads();
        }
        if (t == 0) partials[blk2] = sRed[0];
    }
}

__global__ __launch_bounds__(THREADS)
void chamfer_b(const float* __restrict__ centerMin,
               const float* __restrict__ partials,
               float* __restrict__ out) {
    __shared__ float sRed[THREADS];
    const int t = threadIdx.x;
    float s = centerMin[t] + centerMin[t + THREADS];          // 512 center mins
    for (int i = t; i < R2B; i += THREADS) s += partials[i];  // fixed assignment
    sRed[t] = s;
    __syncthreads();
    for (int st = THREADS / 2; st > 0; st >>= 1) {
        if (t < st) sRed[t] += sRed[t + st];
        __syncthreads();
    }
    if (t == 0) out[0] = 0.5f * sRed[0];                      // mean over B=2
}

extern "C" void kernel_launch(void* const* d_in, const int* in_sizes, int n_in,
                              void* d_out, int out_size, void* d_ws, size_t ws_size,
                              hipStream_t stream) {
    const float* target = (const float*)d_in[0];   // [2,1,240,320] fp32
    const float* edges  = (const float*)d_in[1];   // [2,257] fp32
    float* out = (float*)d_out;

    float* centerMin = (float*)d_ws;                      // 512 floats
    float* partials  = (float*)((char*)d_ws + 2048);      // 600 floats

    chamfer_a<<<NBLOCKS, THREADS, 0, stream>>>(target, edges, centerMin, partials);
    chamfer_b<<<1, THREADS, 0, stream>>>(centerMin, partials, out);
}